// Round 2
// baseline (153.609 us; speedup 1.0000x reference)
//
#include <hip/hip_runtime.h>
#include <math.h>

// AntiAliasInterpolation2d: 13x13 separable gaussian blur (sigma=1.5, zero-pad 6)
// + nearest 4x downsample, fused. x: (32,512,512,3) f32 -> out: (32,128,128,3) f32.
//
// out[n,i,j,c] = sum_{dy,dx in [-6,6]} w[dy]*w[dx] * x[n, 4i+dy, 4j+dx, c]
//
// Phase-rotated accumulators: rows in quads y=4q+p; row phase p feeds output
// rows q-1..q+2 with static dy. After quad q, A0 (= output row q-1) completes;
// rotate A0<-A1<-A2<-A3<-0.
//
// R2 change vs R1: (a) horizontal window held in four explicit float4 vars with
// static component access (R1's float-array + reinterpret_cast pattern risked
// SROA failure -> scratch spill); (b) global staging loads are float4
// (global_load_dwordx4), scattered to planar LDS with 16 scalar ds_writes.

namespace {
constexpr int N_IMG    = 32;
constexpr int H_IN     = 512;
constexpr int W_IN     = 512;
constexpr int C_CH     = 3;
constexpr int H_OUT    = 128;
constexpr int W_OUT    = 128;
constexpr int T_ROWS   = 8;                 // output rows per block (band)
constexpr int BANDS    = H_OUT / T_ROWS;    // 16
constexpr int PITCH    = 532;               // floats per channel plane; %4==0; >=524
constexpr int ROW_ELEMS = W_IN * C_CH;      // 1536
constexpr int NTHREADS = 384;               // one thread per (j,c) output lane
constexpr int LDS_FLOATS = 2 * 4 * 3 * PITCH; // 2 buffers x 4 rows x 3 planes
}

__global__ __launch_bounds__(NTHREADS, 3)
void aa_blur_down(const float* __restrict__ in, float* __restrict__ out) {
  // lds[((b*4 + p)*3 + c)*PITCH + (x + 8)] -- planar per-channel rows,
  // x in [-8, 524): 8-float front halo keeps the 4*j window float4-aligned.
  __shared__ __align__(16) float lds[LDS_FLOATS];

  const int tid = threadIdx.x;
  const int j   = tid / 3;      // output column 0..127
  const int c   = tid % 3;      // channel
  const int n    = blockIdx.x / BANDS;
  const int band = blockIdx.x % BANDS;
  const int i0   = band * T_ROWS;

  // normalized 1D gaussian weights (13 taps), all-static use -> registers
  float wt[13];
  {
    float s = 0.f;
#pragma unroll
    for (int r = 0; r < 13; ++r) {
      const float d = (float)r - 6.0f;
      wt[r] = expf(-d * d * (1.0f / 4.5f));
      s += wt[r];
    }
    const float inv = 1.0f / s;
#pragma unroll
    for (int r = 0; r < 13; ++r) wt[r] *= inv;
  }

  const int qstart = i0 - 2;          // first quad feeding output row i0
  const int qend   = i0 + T_ROWS;     // last quad feeding output row i0+T-1
  const float* img = in + (size_t)n * H_IN * ROW_ELEMS;

  // zero LDS once: establishes the x-halo zeros (zero padding)
  for (int idx = tid; idx < LDS_FLOATS; idx += NTHREADS) lds[idx] = 0.f;
  __syncthreads();

  // staging registers: 4 rows x one float4 per thread (row m, floats 4t..4t+3)
  float4 pre4[4];

  auto load_quad = [&](int q) {
#pragma unroll
    for (int m = 0; m < 4; ++m) {
      const int y = 4 * q + m;
      if (y >= 0 && y < H_IN) {       // wave-uniform predicate (zero row padding)
        pre4[m] = reinterpret_cast<const float4*>(img + (size_t)y * ROW_ELEMS)[tid];
      } else {
        pre4[m] = make_float4(0.f, 0.f, 0.f, 0.f);
      }
    }
  };

  // scatter interleaved float4 (elements g=4t..4t+3, c=g%3, x=g/3) to planar LDS
  const int c0 = tid % 3;             // == (4*tid) % 3
  const int x0 = (4 * tid) / 3;
  auto store_quad = [&](int b) {
#pragma unroll
    for (int m = 0; m < 4; ++m) {
      const int rowbase = (b * 4 + m) * 3 * PITCH;
      float v0 = pre4[m].x, v1 = pre4[m].y, v2 = pre4[m].z, v3 = pre4[m].w;
#pragma unroll
      for (int e = 0; e < 4; ++e) {
        const int ce = c0 + e;
        const int cc = (ce >= 3) ? ce - 3 : ce;
        const int xx = x0 + ((ce >= 3) ? 1 : 0);
        const float v = (e == 0) ? v0 : (e == 1) ? v1 : (e == 2) ? v2 : v3;
        lds[rowbase + cc * PITCH + xx + 8] = v;
      }
    }
  };

  load_quad(qstart);
  store_quad(0);
  __syncthreads();

  float A0 = 0.f, A1 = 0.f, A2 = 0.f, A3 = 0.f;

  for (int q = qstart; q <= qend; ++q) {
    const int b = (q - qstart) & 1;
    const bool more = (q < qend);
    if (more) load_quad(q + 1);       // prefetch next quad during compute

    // horizontal 13-tap conv for the 4 rows of this quad.
    // window x in [4j-8, 4j+8) == padded indices [4j, 4j+16); taps at [2..14].
    float h[4];
#pragma unroll
    for (int p = 0; p < 4; ++p) {
      const float4* plane4 =
          reinterpret_cast<const float4*>(&lds[((b * 4 + p) * 3 + c) * PITCH + 4 * j]);
      const float4 wa = plane4[0];
      const float4 wb = plane4[1];
      const float4 wc = plane4[2];
      const float4 wd = plane4[3];
      float hh;
      hh = wt[0] * wa.z;
      hh = fmaf(wt[1],  wa.w, hh);
      hh = fmaf(wt[2],  wb.x, hh);
      hh = fmaf(wt[3],  wb.y, hh);
      hh = fmaf(wt[4],  wb.z, hh);
      hh = fmaf(wt[5],  wb.w, hh);
      hh = fmaf(wt[6],  wc.x, hh);
      hh = fmaf(wt[7],  wc.y, hh);
      hh = fmaf(wt[8],  wc.z, hh);
      hh = fmaf(wt[9],  wc.w, hh);
      hh = fmaf(wt[10], wd.x, hh);
      hh = fmaf(wt[11], wd.y, hh);
      hh = fmaf(wt[12], wd.z, hh);
      h[p] = hh;
    }

    // vertical accumulation, all weights static
    A0 = fmaf(wt[10], h[0], A0); A0 = fmaf(wt[11], h[1], A0); A0 = fmaf(wt[12], h[2], A0);
    A1 = fmaf(wt[6],  h[0], A1); A1 = fmaf(wt[7],  h[1], A1); A1 = fmaf(wt[8],  h[2], A1); A1 = fmaf(wt[9], h[3], A1);
    A2 = fmaf(wt[2],  h[0], A2); A2 = fmaf(wt[3],  h[1], A2); A2 = fmaf(wt[4],  h[2], A2); A2 = fmaf(wt[5], h[3], A2);
    A3 = fmaf(wt[0],  h[2], A3); A3 = fmaf(wt[1],  h[3], A3);

    // output row q-1 is complete after this quad
    const int i_out = q - 1;
    if (i_out >= i0) {                // i_out <= i0+T-1 always holds
      out[(size_t)(n * H_OUT + i_out) * (W_OUT * C_CH) + tid] = A0;
    }
    A0 = A1; A1 = A2; A2 = A3; A3 = 0.f;

    if (more) store_quad(b ^ 1);      // fill the other buffer
    __syncthreads();                  // one barrier per quad (double-buffered)
  }
}

extern "C" void kernel_launch(void* const* d_in, const int* in_sizes, int n_in,
                              void* d_out, int out_size, void* d_ws, size_t ws_size,
                              hipStream_t stream) {
  const float* x = (const float*)d_in[0];
  float* out = (float*)d_out;
  (void)in_sizes; (void)n_in; (void)out_size; (void)d_ws; (void)ws_size;
  hipLaunchKernelGGL(aa_blur_down, dim3(N_IMG * BANDS), dim3(NTHREADS), 0, stream, x, out);
}

// Round 3
// 151.748 us; speedup vs baseline: 1.0123x; 1.0123x over previous
//
#include <hip/hip_runtime.h>
#include <math.h>

// AntiAliasInterpolation2d: 13x13 separable gaussian blur (sigma=1.5, zero-pad 6)
// + nearest 4x downsample, fused. x: (32,512,512,3) f32 -> out: (32,128,128,3) f32.
//
// out[n,i,j,c] = sum_{dy,dx in [-6,6]} w[dy]*w[dx] * x[n, 4i+dy, 4j+dx, c]
//
// Phase-rotated accumulators: rows in quads y=4q+p; row phase p feeds output
// rows q-1..q+2 with static dy. After quad q, A0 (= output row q-1) completes;
// rotate A0<-A1<-A2<-A3<-0.
//
// R3 change vs R2: prefetch distance 2 through registers. Two staging register
// sets P0/P1; the global load for quad q+2 is issued at step q and its ds_write
// happens at step q+2 -> ~2 quad-steps (>2000 cyc) of slack vs ~900 cyc HBM
// latency, so the vmcnt wait before the LDS store is ~free. Main loop is
// 2-unrolled so P0/P1 alternate without register moves. Same double-buffered
// LDS, one barrier per quad.

namespace {
constexpr int N_IMG    = 32;
constexpr int H_IN     = 512;
constexpr int W_IN     = 512;
constexpr int C_CH     = 3;
constexpr int H_OUT    = 128;
constexpr int W_OUT    = 128;
constexpr int T_ROWS   = 8;                 // output rows per block (band)
constexpr int BANDS    = H_OUT / T_ROWS;    // 16
constexpr int PITCH    = 532;               // floats per channel plane; %4==0; >=524
constexpr int ROW_ELEMS = W_IN * C_CH;      // 1536
constexpr int NTHREADS = 384;               // one thread per (j,c) output lane
constexpr int LDS_FLOATS = 2 * 4 * 3 * PITCH; // 2 buffers x 4 rows x 3 planes
}

__global__ __launch_bounds__(NTHREADS, 3)
void aa_blur_down(const float* __restrict__ in, float* __restrict__ out) {
  // lds[((b*4 + p)*3 + c)*PITCH + (x + 8)] -- planar per-channel rows,
  // x in [-8, 524): 8-float front halo keeps the 4*j window float4-aligned.
  __shared__ __align__(16) float lds[LDS_FLOATS];

  const int tid = threadIdx.x;
  const int j   = tid / 3;      // output column 0..127
  const int c   = tid % 3;      // channel
  const int n    = blockIdx.x / BANDS;
  const int band = blockIdx.x % BANDS;
  const int i0   = band * T_ROWS;

  // normalized 1D gaussian weights (13 taps), all-static use -> registers
  float wt[13];
  {
    float s = 0.f;
#pragma unroll
    for (int r = 0; r < 13; ++r) {
      const float d = (float)r - 6.0f;
      wt[r] = expf(-d * d * (1.0f / 4.5f));
      s += wt[r];
    }
    const float inv = 1.0f / s;
#pragma unroll
    for (int r = 0; r < 13; ++r) wt[r] *= inv;
  }

  const int qstart = i0 - 2;          // first quad feeding output row i0
  const int qend   = i0 + T_ROWS;     // last quad feeding output row i0+T-1 (qstart+10)
  const float* img = in + (size_t)n * H_IN * ROW_ELEMS;

  // zero LDS once: establishes the x-halo zeros (zero padding)
  for (int idx = tid; idx < LDS_FLOATS; idx += NTHREADS) lds[idx] = 0.f;
  __syncthreads();

  // staging registers: 4 rows x one float4 per thread (row m, floats 4t..4t+3)
  float4 P0[4], P1[4];

  auto load_quad = [&](float4 (&P)[4], int q) {
#pragma unroll
    for (int m = 0; m < 4; ++m) {
      const int y = 4 * q + m;
      if (y >= 0 && y < H_IN) {       // block-uniform predicate (zero row padding)
        P[m] = reinterpret_cast<const float4*>(img + (size_t)y * ROW_ELEMS)[tid];
      } else {
        P[m] = make_float4(0.f, 0.f, 0.f, 0.f);
      }
    }
  };

  // scatter interleaved float4 (elements g=4t..4t+3, c=g%3, x=g/3) to planar LDS
  const int c0 = tid % 3;             // == (4*tid) % 3
  const int x0 = (4 * tid) / 3;
  auto store_quad = [&](const float4 (&P)[4], int b) {
#pragma unroll
    for (int m = 0; m < 4; ++m) {
      const int rowbase = (b * 4 + m) * 3 * PITCH;
      const float v0 = P[m].x, v1 = P[m].y, v2 = P[m].z, v3 = P[m].w;
#pragma unroll
      for (int e = 0; e < 4; ++e) {
        const int ce = c0 + e;
        const int cc = (ce >= 3) ? ce - 3 : ce;
        const int xx = x0 + ((ce >= 3) ? 1 : 0);
        const float v = (e == 0) ? v0 : (e == 1) ? v1 : (e == 2) ? v2 : v3;
        lds[rowbase + cc * PITCH + xx + 8] = v;
      }
    }
  };

  float A0 = 0.f, A1 = 0.f, A2 = 0.f, A3 = 0.f;

  // compute quad q from LDS buffer b: horizontal 13-tap conv for 4 rows,
  // vertical accumulation with static weights, emit output row q-1, rotate.
  auto compute_quad = [&](int q, int b) {
    float h[4];
#pragma unroll
    for (int p = 0; p < 4; ++p) {
      const float4* plane4 =
          reinterpret_cast<const float4*>(&lds[((b * 4 + p) * 3 + c) * PITCH + 4 * j]);
      const float4 wa = plane4[0];
      const float4 wb = plane4[1];
      const float4 wc = plane4[2];
      const float4 wd = plane4[3];
      float hh;
      hh = wt[0] * wa.z;
      hh = fmaf(wt[1],  wa.w, hh);
      hh = fmaf(wt[2],  wb.x, hh);
      hh = fmaf(wt[3],  wb.y, hh);
      hh = fmaf(wt[4],  wb.z, hh);
      hh = fmaf(wt[5],  wb.w, hh);
      hh = fmaf(wt[6],  wc.x, hh);
      hh = fmaf(wt[7],  wc.y, hh);
      hh = fmaf(wt[8],  wc.z, hh);
      hh = fmaf(wt[9],  wc.w, hh);
      hh = fmaf(wt[10], wd.x, hh);
      hh = fmaf(wt[11], wd.y, hh);
      hh = fmaf(wt[12], wd.z, hh);
      h[p] = hh;
    }

    A0 = fmaf(wt[10], h[0], A0); A0 = fmaf(wt[11], h[1], A0); A0 = fmaf(wt[12], h[2], A0);
    A1 = fmaf(wt[6],  h[0], A1); A1 = fmaf(wt[7],  h[1], A1); A1 = fmaf(wt[8],  h[2], A1); A1 = fmaf(wt[9], h[3], A1);
    A2 = fmaf(wt[2],  h[0], A2); A2 = fmaf(wt[3],  h[1], A2); A2 = fmaf(wt[4],  h[2], A2); A2 = fmaf(wt[5], h[3], A2);
    A3 = fmaf(wt[0],  h[2], A3); A3 = fmaf(wt[1],  h[3], A3);

    const int i_out = q - 1;          // complete after this quad
    if (i_out >= i0) {
      out[(size_t)(n * H_OUT + i_out) * (W_OUT * C_CH) + tid] = A0;
    }
    A0 = A1; A1 = A2; A2 = A3; A3 = 0.f;
  };

  // Pipeline prologue: buf0 <- quad qs; P1 holds quad qs+1 (in flight).
  load_quad(P0, qstart);
  store_quad(P0, 0);
  load_quad(P1, qstart + 1);
  __syncthreads();                    // buf0 ready

  // Steady state, 2-unrolled. Invariant at top of step q (buffer b=(q-qstart)&1):
  //   LDS buffer b holds quad q; the "other" register set holds quad q+1.
  for (int qq = qstart; ; qq += 2) {
    // step A: compute quad qq from buf0-parity buffer
    if (qq + 2 <= qend) load_quad(P0, qq + 2);   // in flight until step q+2
    compute_quad(qq, (qq - qstart) & 1);
    if (qq + 1 <= qend) store_quad(P1, (qq + 1 - qstart) & 1);
    __syncthreads();
    if (qq + 1 > qend) break;

    // step B: compute quad qq+1
    if (qq + 3 <= qend) load_quad(P1, qq + 3);
    compute_quad(qq + 1, (qq + 1 - qstart) & 1);
    if (qq + 2 <= qend) store_quad(P0, (qq + 2 - qstart) & 1);
    __syncthreads();
    if (qq + 2 > qend) break;
  }
}

extern "C" void kernel_launch(void* const* d_in, const int* in_sizes, int n_in,
                              void* d_out, int out_size, void* d_ws, size_t ws_size,
                              hipStream_t stream) {
  const float* x = (const float*)d_in[0];
  float* out = (float*)d_out;
  (void)in_sizes; (void)n_in; (void)out_size; (void)d_ws; (void)ws_size;
  hipLaunchKernelGGL(aa_blur_down, dim3(N_IMG * BANDS), dim3(NTHREADS), 0, stream, x, out);
}

// Round 4
// 146.655 us; speedup vs baseline: 1.0474x; 1.0347x over previous
//
#include <hip/hip_runtime.h>
#include <math.h>

// AntiAliasInterpolation2d: 13x13 separable gaussian blur (sigma=1.5, zero-pad 6)
// + nearest 4x downsample, fused. x: (32,512,512,3) f32 -> out: (32,128,128,3) f32.
//
// out[n,i,j,c] = sum_{dy,dx} w[dy]*w[dx] * x[n, 4i+dy, 4j+dx, c]
//
// R4 restructure: VERTICAL conv first, straight from global float4 loads into
// rolling float4 accumulators (no LDS staging of input rows -- vertical conv
// needs no channel deinterleave). Only the 128 vertically-blurred rows make an
// LDS round-trip (planar deinterleave) for the horizontal conv: 4x fewer LDS
// reads/writes than R3 and 8 barriers/block instead of 11.
//
// Input rows in quads y=4q+p; phase p feeds output rows q-1..q+2 with static
// weights (A0<-i=q-1, A1<-q, A2<-q+1, A3<-q+2; rotate after each quad). The
// 11-quad loop is fully unrolled: rotations become SSA renames, and loads/FMAs
// whose target output rows are discarded are statically pruned.

namespace {
constexpr int N_IMG   = 32;
constexpr int H_IN    = 512;
constexpr int W_IN    = 512;
constexpr int C_CH    = 3;
constexpr int H_OUT   = 128;
constexpr int W_OUT   = 128;
constexpr int T_ROWS  = 8;                // output rows per block
constexpr int BANDS   = H_OUT / T_ROWS;   // 16
constexpr int PITCH   = 532;              // padded plane: 8 front + 512 + 4 back, %4==0
constexpr int ROW_ELEMS = W_IN * C_CH;    // 1536
constexpr int NTHREADS = 384;             // thread t owns flat floats 4t..4t+3 of a row
constexpr int LDS_FLOATS = 2 * 3 * PITCH; // 2 row-buffers x 3 channel planes
}

__device__ __forceinline__ float4 f4fma(float w, const float4& p, const float4& a) {
  return make_float4(fmaf(w, p.x, a.x), fmaf(w, p.y, a.y),
                     fmaf(w, p.z, a.z), fmaf(w, p.w, a.w));
}

__global__ __launch_bounds__(NTHREADS, 2)
void aa_blur_down(const float* __restrict__ in, float* __restrict__ out) {
  __shared__ __align__(16) float lds[LDS_FLOATS];

  const int tid = threadIdx.x;
  const int j   = tid / 3;                // output column 0..127
  const int c   = tid % 3;                // channel
  const int n    = blockIdx.x / BANDS;
  const int band = blockIdx.x % BANDS;
  const int i0   = band * T_ROWS;

  // normalized 1D gaussian weights (13 taps), static use -> registers
  float wt[13];
  {
    float s = 0.f;
#pragma unroll
    for (int r = 0; r < 13; ++r) {
      const float d = (float)r - 6.0f;
      wt[r] = expf(-d * d * (1.0f / 4.5f));
      s += wt[r];
    }
    const float inv = 1.0f / s;
#pragma unroll
    for (int r = 0; r < 13; ++r) wt[r] *= inv;
  }

  const int qstart = i0 - 2;              // quads qstart..qstart+10
  const float* img = in + (size_t)n * H_IN * ROW_ELEMS;

  // zero LDS once (establishes the column-halo zeros); halos are never rewritten
  for (int idx = tid; idx < LDS_FLOATS; idx += NTHREADS) lds[idx] = 0.f;
  __syncthreads();

  // planar scatter offsets for this thread's float4 (flat g = 4t+e: c=g%3, x=g/3)
  int off_e[4];
#pragma unroll
  for (int e = 0; e < 4; ++e) {
    const int ce = c + e;                 // (4t+e)%3 path
    const int cc = (ce >= 3) ? ce - 3 : ce;
    const int xx = (4 * tid) / 3 + ((ce >= 3) ? 1 : 0);
    off_e[e] = cc * PITCH + xx + 8;
  }

  // row (s,m) is needed unless statically dead: s==0 rows feed only discarded
  // outputs for m<2; s==10 row m==3 feeds only discarded outputs.
  float4 P[3][4];
  auto loadq = [&](int slot, int s) {
    const int q = qstart + s;
#pragma unroll
    for (int m = 0; m < 4; ++m) {
      const bool dead = (s == 0 && m < 2) || (s == 10 && m == 3);
      const int y = 4 * q + m;
      if (!dead && (unsigned)y < (unsigned)H_IN) {
        P[slot][m] = reinterpret_cast<const float4*>(img + (size_t)y * ROW_ELEMS)[tid];
      } else {
        P[slot][m] = make_float4(0.f, 0.f, 0.f, 0.f);
      }
    }
  };

  float4 A0 = make_float4(0,0,0,0), A1 = A0, A2 = A0, A3 = A0;

  loadq(0, 0);
  loadq(1, 1);

#pragma unroll
  for (int s = 0; s <= 10; ++s) {
    if (s + 2 <= 10) loadq((s + 2) % 3, s + 2);   // distance-2 prefetch, ring of 3

    const float4 p0 = P[s % 3][0];
    const float4 p1 = P[s % 3][1];
    const float4 p2 = P[s % 3][2];
    const float4 p3 = P[s % 3][3];

    // vertical accumulation; statically pruned to live output rows
    if (s >= 3)           { A0 = f4fma(wt[10], p0, A0); A0 = f4fma(wt[11], p1, A0); A0 = f4fma(wt[12], p2, A0); }
    if (s >= 2 && s <= 9) { A1 = f4fma(wt[6],  p0, A1); A1 = f4fma(wt[7],  p1, A1); A1 = f4fma(wt[8],  p2, A1); A1 = f4fma(wt[9], p3, A1); }
    if (s >= 1 && s <= 8) { A2 = f4fma(wt[2],  p0, A2); A2 = f4fma(wt[3],  p1, A2); A2 = f4fma(wt[4],  p2, A2); A2 = f4fma(wt[5], p3, A2); }
    if (s <= 7)           { A3 = f4fma(wt[0],  p2, A3); A3 = f4fma(wt[1],  p3, A3); }

    if (s >= 3) {
      // A0 = vertically blurred row i, flat floats 4t..4t+3
      const int i = i0 + s - 3;
      const int b = (s - 3) & 1;          // double-buffered by row parity
      float* buf = &lds[b * 3 * PITCH];
      buf[off_e[0]] = A0.x;
      buf[off_e[1]] = A0.y;
      buf[off_e[2]] = A0.z;
      buf[off_e[3]] = A0.w;
      __syncthreads();

      // horizontal 13-tap conv: padded window [4j, 4j+16), taps at [2..14]
      const float4* pl = reinterpret_cast<const float4*>(&buf[c * PITCH + 4 * j]);
      const float4 wa = pl[0];
      const float4 wb = pl[1];
      const float4 wc = pl[2];
      const float4 wd = pl[3];
      float hh;
      hh = wt[0] * wa.z;
      hh = fmaf(wt[1],  wa.w, hh);
      hh = fmaf(wt[2],  wb.x, hh);
      hh = fmaf(wt[3],  wb.y, hh);
      hh = fmaf(wt[4],  wb.z, hh);
      hh = fmaf(wt[5],  wb.w, hh);
      hh = fmaf(wt[6],  wc.x, hh);
      hh = fmaf(wt[7],  wc.y, hh);
      hh = fmaf(wt[8],  wc.z, hh);
      hh = fmaf(wt[9],  wc.w, hh);
      hh = fmaf(wt[10], wd.x, hh);
      hh = fmaf(wt[11], wd.y, hh);
      hh = fmaf(wt[12], wd.z, hh);
      out[(size_t)(n * H_OUT + i) * (W_OUT * C_CH) + tid] = hh;
    }

    A0 = A1; A1 = A2; A2 = A3; A3 = make_float4(0.f, 0.f, 0.f, 0.f);
  }
}

extern "C" void kernel_launch(void* const* d_in, const int* in_sizes, int n_in,
                              void* d_out, int out_size, void* d_ws, size_t ws_size,
                              hipStream_t stream) {
  const float* x = (const float*)d_in[0];
  float* out = (float*)d_out;
  (void)in_sizes; (void)n_in; (void)out_size; (void)d_ws; (void)ws_size;
  hipLaunchKernelGGL(aa_blur_down, dim3(N_IMG * BANDS), dim3(NTHREADS), 0, stream, x, out);
}